// Round 10
// baseline (215.230 us; speedup 1.0000x reference)
//
#include <hip/hip_runtime.h>
#include <stdint.h>

#define CC 256
#define NNq 4096

typedef float f32x4 __attribute__((ext_vector_type(4)));
typedef short bf16x8 __attribute__((ext_vector_type(8)));

#define MFMA16(a, b, c) __builtin_amdgcn_mfma_f32_16x16x32_bf16(a, b, c, 0, 0, 0)

static __device__ __forceinline__ short f2bf(float f) {
  unsigned u = __builtin_bit_cast(unsigned, f);
  u += 0x7fffu + ((u >> 16) & 1u);   // RNE
  return (short)(u >> 16);
}
static __device__ __forceinline__ float bf2f(short s) {
  return __builtin_bit_cast(float, ((unsigned)(unsigned short)s) << 16);
}

// barrier that does NOT drain vmcnt; sched_barrier(0) fences motion (rule 18).
#define SBAR() do { \
  __builtin_amdgcn_sched_barrier(0); \
  asm volatile("s_waitcnt lgkmcnt(0)" ::: "memory"); \
  __builtin_amdgcn_s_barrier(); \
  __builtin_amdgcn_sched_barrier(0); \
} while (0)

// ---------------------------------------------------------------------------
// Kernel 1: projections (unchanged, proven).
// ---------------------------------------------------------------------------
#define XSTR 66

__global__ __launch_bounds__(256) void proj_kernel(
    const float* __restrict__ x,
    const float* __restrict__ Wq, const float* __restrict__ bq,
    const float* __restrict__ Wk, const float* __restrict__ bk,
    const float* __restrict__ Wv, const float* __restrict__ bv,
    unsigned short* __restrict__ qh_, unsigned short* __restrict__ ql_,
    unsigned short* __restrict__ kh_, unsigned short* __restrict__ kl_,
    unsigned short* __restrict__ v5)
{
  __shared__ float xs[256 * XSTR];
  const int t = threadIdx.x;
  const int b = blockIdx.x >> 6;
  const int n0 = (blockIdx.x & 63) << 6;
  const float L2E = 1.4426950408889634f;

  const float* xb = x + ((size_t)b * CC) * NNq + n0;
#pragma unroll
  for (int i = 0; i < 16; ++i) {
    int fi = i * 256 + t;
    int c = fi >> 4, nv = (fi & 15) << 2;
    float4 v4 = *(const float4*)(xb + (size_t)c * NNq + nv);
    float* d = &xs[c * XSTR + nv];
    d[0] = v4.x; d[1] = v4.y; d[2] = v4.z; d[3] = v4.w;
  }
  __syncthreads();

  const int w = t >> 6, l = t & 63;
  const int l15 = l & 15, l4 = l >> 4;

  f32x4 acc[5][4];
#pragma unroll
  for (int r5 = 0; r5 < 5; ++r5) {
    int rt = w * 5 + r5;
    const float* bias; float bscale;
    if (rt < 16)      { bias = bv + rt * 16;        bscale = 1.f; }
    else if (rt < 18) { bias = bq + (rt - 16) * 16; bscale = L2E; }
    else              { bias = bk + (rt - 18) * 16; bscale = 1.f; }
#pragma unroll
    for (int j = 0; j < 4; ++j) {
      float bval = bias[l4 * 4 + j] * bscale;
#pragma unroll
      for (int nt = 0; nt < 4; ++nt) acc[r5][nt][j] = bval;
    }
  }

#pragma unroll 1
  for (int ks = 0; ks < 8; ++ks) {
    bf16x8 ah[5], al[5];
#pragma unroll
    for (int r5 = 0; r5 < 5; ++r5) {
      int rt = w * 5 + r5;
      const float* wrow; float wscale;
      if (rt < 16)      { wrow = Wv + (size_t)(rt * 16 + l15) * 256;        wscale = 1.f; }
      else if (rt < 18) { wrow = Wq + (size_t)((rt - 16) * 16 + l15) * 256; wscale = L2E; }
      else              { wrow = Wk + (size_t)((rt - 18) * 16 + l15) * 256; wscale = 1.f; }
      const float* src = wrow + ks * 32 + l4 * 8;
#pragma unroll
      for (int i = 0; i < 8; ++i) {
        float v = src[i] * wscale;
        short hh = f2bf(v);
        ah[r5][i] = hh;
        al[r5][i] = f2bf(v - bf2f(hh));
      }
    }
#pragma unroll
    for (int nt = 0; nt < 4; ++nt) {
      bf16x8 bh, bl;
#pragma unroll
      for (int i = 0; i < 8; ++i) {
        float v = xs[(ks * 32 + l4 * 8 + i) * XSTR + nt * 16 + l15];
        short hh = f2bf(v);
        bh[i] = hh;
        bl[i] = f2bf(v - bf2f(hh));
      }
#pragma unroll
      for (int r5 = 0; r5 < 5; ++r5) {
        acc[r5][nt] = MFMA16(ah[r5], bl, acc[r5][nt]);
        acc[r5][nt] = MFMA16(al[r5], bh, acc[r5][nt]);
        acc[r5][nt] = MFMA16(ah[r5], bh, acc[r5][nt]);
      }
    }
  }

#pragma unroll
  for (int r5 = 0; r5 < 5; ++r5) {
    int rt = w * 5 + r5;
#pragma unroll
    for (int nt = 0; nt < 4; ++nt) {
      int n = n0 + nt * 16 + l15;
#pragma unroll
      for (int j = 0; j < 4; ++j) {
        float v = acc[r5][nt][j];
        int sub = l4 * 4 + j;
        if (rt < 16) {
          int c = rt * 16 + sub;
          size_t o = (((size_t)b * 128 + (n >> 5)) * 256 + c) * 32 + (n & 31);
          v5[o] = (unsigned short)f2bf(v);
        } else {
          short hh = f2bf(v);
          short lo = f2bf(v - bf2f(hh));
          unsigned short* dh = (rt < 18) ? qh_ : kh_;
          unsigned short* dl = (rt < 18) ? ql_ : kl_;
          int d = ((rt < 18) ? (rt - 16) : (rt - 18)) * 16 + sub;
          size_t o = ((size_t)b * NNq + n) * 32 + d;
          dh[o] = (unsigned short)hh;
          dl[o] = (unsigned short)lo;
        }
      }
    }
  }
}

// ---------------------------------------------------------------------------
// Kernel 2 (A): fused E + row-sums + UNNORMALIZED PV + epilogue. NO global
// stores in the loop (the r7-r9 limiter: loads+stores share in-order vmcnt,
// so load-waits drained the attn store stream every iteration).
// out = (sum_m p~ v)/S with p~ = exp2(e-64); S applied in the epilogue.
// Exports Crow = 64+log2(S) for the attention-writer kernel.
// Structure: r9's pipelined loop (proven): 512 blocks x 8 waves, 32-row tile,
// 128-m chunks, double-buffered swizzled p~ LDS tile, 1 SBAR/chunk, k/v
// prefetch 1-2 ahead, setprio around PV.
// ---------------------------------------------------------------------------
__global__ __launch_bounds__(512, 4) void pv_kernel(
    const unsigned short* __restrict__ qh_, const unsigned short* __restrict__ ql_,
    const unsigned short* __restrict__ kh_, const unsigned short* __restrict__ kl_,
    const unsigned short* __restrict__ v5, const float* __restrict__ x,
    const float* __restrict__ gamma, float* __restrict__ Crow,
    float* __restrict__ out)
{
  __shared__ __align__(16) unsigned short p_lds[2][4096]; // [par][32 n][128 m] bf16, XOR-swz
  __shared__ float sums_lds[8][32];

  const int t = threadIdx.x, w = t >> 6, l = t & 63;
  const int l15 = l & 15, l4 = l >> 4;
  const int sb = ((blockIdx.x & 7) << 6) | (blockIdx.x >> 3);  // 512%8==0, bijective
  const int b = sb >> 7;
  const int n0 = (sb & 127) << 5;
  const int g = w >> 2, h = w & 3;
  const int h32 = h * 32;

  const unsigned short* khb = kh_ + (size_t)b * NNq * 32;
  const unsigned short* klb = kl_ + (size_t)b * NNq * 32;
  const unsigned short* vbb = v5 + (size_t)b * 1048576;

  const size_t qbase = ((size_t)b * NNq + n0 + g * 16 + l15) * 32 + l4 * 8;
  const bf16x8 qh = *(const bf16x8*)(qh_ + qbase);
  const bf16x8 qlo = *(const bf16x8*)(ql_ + qbase);

  f32x4 acc[2][2];   // c = w*32 + ct*16 + l4*4 + j ; n = n0 + nt*16 + l15
#pragma unroll
  for (int ct = 0; ct < 2; ++ct)
#pragma unroll
    for (int nt = 0; nt < 2; ++nt) acc[ct][nt] = f32x4{0.f, 0.f, 0.f, 0.f};

  float sx[4] = {0.f, 0.f, 0.f, 0.f};  // row-sum partials (row = g*16+l4*4+j)
  bf16x8 pw;                           // packed p~ carried E-phase -> pwrite

  auto loadK = [&](int chunk, bf16x8 (&KH)[2], bf16x8 (&KL)[2]) {
#pragma unroll
    for (int sub = 0; sub < 2; ++sub) {
      size_t ko = (size_t)(chunk * 128 + h32 + sub * 16 + l15) * 32 + l4 * 8;
      KH[sub] = *(const bf16x8*)(khb + ko);
      KL[sub] = *(const bf16x8*)(klb + ko);
    }
  };
  auto estep = [&](const bf16x8 (&KH)[2], const bf16x8 (&KL)[2]) {
#pragma unroll
    for (int sub = 0; sub < 2; ++sub) {
      f32x4 e = {0.f, 0.f, 0.f, 0.f};
      e = MFMA16(qh, KL[sub], e);
      e = MFMA16(qlo, KH[sub], e);
      e = MFMA16(qh, KH[sub], e);
#pragma unroll
      for (int j = 0; j < 4; ++j) {
        float p = exp2f(e[j] - 64.0f);   // unnormalized; S folded in later
        sx[j] += p;
        pw[sub * 4 + j] = f2bf(p);
      }
    }
  };
  auto pwrite = [&](int par) {
    char* pld = (char*)p_lds[par];
#pragma unroll
    for (int sub = 0; sub < 2; ++sub)
#pragma unroll
      for (int j = 0; j < 4; ++j) {
        int nl = g * 16 + l4 * 4 + j;
        int ml = h32 + sub * 16 + l15;
        int byteo = nl * 256 + ((ml * 2) ^ ((nl & 7) << 4));
        *(unsigned short*)(pld + byteo) = (unsigned short)pw[sub * 4 + j];
      }
  };

  bf16x8 kAh[2], kAl[2];
  loadK(0, kAh, kAl);
  estep(kAh, kAl);      // chunk 0
  pwrite(0);
  loadK(1, kAh, kAl);

#pragma unroll 1
  for (int it = 0; it < 32; ++it) {
    // (a) first half of vf(i) loads
    bf16x8 vfA[2][2], vfB[2][2];
#pragma unroll
    for (int ct = 0; ct < 2; ++ct)
#pragma unroll
      for (int ms = 0; ms < 2; ++ms) {
        size_t vo = (size_t)(it * 4 + ms) * 8192 +
                    (size_t)(w * 32 + ct * 16 + l15) * 32 + l4 * 8;
        vfA[ct][ms] = *(const bf16x8*)(vbb + vo);
      }
    // (b) k(i+2) prefetch
    bf16x8 kBh[2], kBl[2];
    loadK((it + 2) & 31, kBh, kBl);
    // (c) E(i+1): MFMA + exp + sums + pack (NO global stores)
    if (it < 31) estep(kAh, kAl);
    // second half of vf(i)
#pragma unroll
    for (int ct = 0; ct < 2; ++ct)
#pragma unroll
      for (int ms = 2; ms < 4; ++ms) {
        size_t vo = (size_t)(it * 4 + ms) * 8192 +
                    (size_t)(w * 32 + ct * 16 + l15) * 32 + l4 * 8;
        vfB[ct][ms - 2] = *(const bf16x8*)(vbb + vo);
      }
    SBAR();
    if (it < 31) pwrite((it + 1) & 1);
    // PV(i)
    char* pl = (char*)p_lds[it & 1];
    __builtin_amdgcn_s_setprio(1);
#pragma unroll
    for (int ms = 0; ms < 4; ++ms) {
      int mbyte = ms * 64 + l4 * 16;
      int o0 = l15 * 256 + (mbyte ^ ((l15 & 7) << 4));
      int o1 = (16 + l15) * 256 + (mbyte ^ (((16 + l15) & 7) << 4));
      bf16x8 pf0 = *(const bf16x8*)(pl + o0);
      bf16x8 pf1 = *(const bf16x8*)(pl + o1);
#pragma unroll
      for (int ct = 0; ct < 2; ++ct) {
        bf16x8 vv = (ms < 2) ? vfA[ct][ms & 1] : vfB[ct][ms & 1];
        acc[ct][0] = MFMA16(vv, pf0, acc[ct][0]);
        acc[ct][1] = MFMA16(vv, pf1, acc[ct][1]);
      }
    }
    __builtin_amdgcn_s_setprio(0);
#pragma unroll
    for (int sub = 0; sub < 2; ++sub) { kAh[sub] = kBh[sub]; kAl[sub] = kBl[sub]; }
  }

  // ---------------- sums merge, normalize, epilogue ----------------
#pragma unroll
  for (int mask = 1; mask < 16; mask <<= 1)
#pragma unroll
    for (int j = 0; j < 4; ++j) sx[j] += __shfl_xor(sx[j], mask);
  if (l15 == 0) {
#pragma unroll
    for (int j = 0; j < 4; ++j) sums_lds[w][g * 16 + l4 * 4 + j] = sx[j];
  }
  __syncthreads();

  float Sinv[2], Sv[2];
#pragma unroll
  for (int nt = 0; nt < 2; ++nt) {
    int r = nt * 16 + l15;
    float S = sums_lds[nt * 4 + 0][r] + sums_lds[nt * 4 + 1][r] +
              sums_lds[nt * 4 + 2][r] + sums_lds[nt * 4 + 3][r];
    Sv[nt] = S;
    Sinv[nt] = 1.0f / S;
  }
  if (w == 0 && l4 == 0) {
    Crow[(size_t)b * NNq + n0 + l15]      = 64.0f + log2f(Sv[0]);
    Crow[(size_t)b * NNq + n0 + 16 + l15] = 64.0f + log2f(Sv[1]);
  }

  const float gm = gamma[0];
#pragma unroll
  for (int ct = 0; ct < 2; ++ct) {
#pragma unroll
    for (int nt = 0; nt < 2; ++nt) {
#pragma unroll
      for (int j = 0; j < 4; ++j) {
        int c = w * 32 + ct * 16 + l4 * 4 + j;
        int n = n0 + nt * 16 + l15;
        size_t go = ((size_t)b * CC + c) * NNq + n;
        float o = acc[ct][nt][j] * Sinv[nt] * gm;
        out[4194304 + go] = o;
        out[go] = o + x[go];
      }
    }
  }
}

// ---------------------------------------------------------------------------
// Kernel 3 (B): pure attention-write stream. Swapped MFMA (A=K, B=Q) puts
// 4 CONSECUTIVE m of one row n in each lane -> one dwordx4 nontemporal store
// per lane (1KB/instr; sub0+sub1 complete each 128B line per row). No LDS,
// no barriers, independent waves; k prefetched 1 iter ahead. 1024 blocks.
// ---------------------------------------------------------------------------
__global__ __launch_bounds__(256, 4) void attn_write_kernel(
    const unsigned short* __restrict__ qh_, const unsigned short* __restrict__ ql_,
    const unsigned short* __restrict__ kh_, const unsigned short* __restrict__ kl_,
    const float* __restrict__ Crow, float* __restrict__ out)
{
  const int t = threadIdx.x, w = t >> 6, l = t & 63;
  const int l15 = l & 15, l4 = l >> 4;
  const int sb = ((blockIdx.x & 7) << 7) | (blockIdx.x >> 3);  // 1024%8==0
  const int b = sb >> 8;
  const int n0 = (sb & 255) << 4;

  const size_t qbase = ((size_t)b * NNq + n0 + l15) * 32 + l4 * 8;
  const bf16x8 qbh = *(const bf16x8*)(qh_ + qbase);   // B-frag: col n=l15, k=d
  const bf16x8 qbl = *(const bf16x8*)(ql_ + qbase);
  const float crn = Crow[(size_t)b * NNq + n0 + l15];
  const unsigned short* khb = kh_ + (size_t)b * NNq * 32;
  const unsigned short* klb = kl_ + (size_t)b * NNq * 32;
  float* arow = out + 8388608 + (size_t)b * NNq * NNq + (size_t)(n0 + l15) * NNq;
  const int m0 = w * 1024;

  bf16x8 kAh[2], kAl[2];
#pragma unroll
  for (int sub = 0; sub < 2; ++sub) {
    size_t ko = (size_t)(m0 + sub * 16 + l15) * 32 + l4 * 8;  // A-frag: row m=l15
    kAh[sub] = *(const bf16x8*)(khb + ko);
    kAl[sub] = *(const bf16x8*)(klb + ko);
  }

#pragma unroll 1
  for (int it = 0; it < 32; ++it) {
    const int mb = m0 + it * 32;
    const int nx = m0 + ((it + 1) & 31) * 32;
    bf16x8 kBh[2], kBl[2];
#pragma unroll
    for (int sub = 0; sub < 2; ++sub) {
      size_t ko = (size_t)(nx + sub * 16 + l15) * 32 + l4 * 8;
      kBh[sub] = *(const bf16x8*)(khb + ko);
      kBl[sub] = *(const bf16x8*)(klb + ko);
    }
#pragma unroll
    for (int sub = 0; sub < 2; ++sub) {
      // swapped: e[j] = E[m = mb+sub*16+l4*4+j][n = n0+l15]
      f32x4 e = {0.f, 0.f, 0.f, 0.f};
      e = MFMA16(kAh[sub], qbl, e);
      e = MFMA16(kAl[sub], qbh, e);
      e = MFMA16(kAh[sub], qbh, e);
      f32x4 p;
#pragma unroll
      for (int j = 0; j < 4; ++j) p[j] = exp2f(e[j] - crn);
      __builtin_nontemporal_store(p, (f32x4*)(arow + mb + sub * 16 + l4 * 4));
    }
#pragma unroll
    for (int sub = 0; sub < 2; ++sub) { kAh[sub] = kBh[sub]; kAl[sub] = kBl[sub]; }
  }
}

extern "C" void kernel_launch(void* const* d_in, const int* in_sizes, int n_in,
                              void* d_out, int out_size, void* d_ws, size_t ws_size,
                              hipStream_t stream) {
  const float* x     = (const float*)d_in[0];
  const float* Wq    = (const float*)d_in[1];
  const float* bq    = (const float*)d_in[2];
  const float* Wk    = (const float*)d_in[3];
  const float* bk    = (const float*)d_in[4];
  const float* Wv    = (const float*)d_in[5];
  const float* bv    = (const float*)d_in[6];
  const float* gamma = (const float*)d_in[7];
  float* out = (float*)d_out;

  char* ws = (char*)d_ws;
  unsigned short* qh   = (unsigned short*)(ws);                    // 1 MB
  unsigned short* ql   = (unsigned short*)(ws + (1u << 20));       // 1 MB
  unsigned short* kh   = (unsigned short*)(ws + (2u << 20));       // 1 MB
  unsigned short* kl   = (unsigned short*)(ws + (3u << 20));       // 1 MB
  unsigned short* v5   = (unsigned short*)(ws + (4u << 20));       // 8 MB
  float* Crow          = (float*)(ws + (12u << 20));               // 64 KB

  proj_kernel<<<256, 256, 0, stream>>>(x, Wq, bq, Wk, bk, Wv, bv, qh, ql, kh, kl, v5);
  pv_kernel<<<512, 512, 0, stream>>>(qh, ql, kh, kl, v5, x, gamma, Crow, out);
  attn_write_kernel<<<1024, 256, 0, stream>>>(qh, ql, kh, kl, Crow, out);
}

// Round 11
// 151.939 us; speedup vs baseline: 1.4166x; 1.4166x over previous
//
#include <hip/hip_runtime.h>
#include <stdint.h>

#define CC 256
#define NNq 4096

typedef float f32x4 __attribute__((ext_vector_type(4)));
typedef short bf16x8 __attribute__((ext_vector_type(8)));

#define MFMA16(a, b, c) __builtin_amdgcn_mfma_f32_16x16x32_bf16(a, b, c, 0, 0, 0)

static __device__ __forceinline__ short f2bf(float f) {
  unsigned u = __builtin_bit_cast(unsigned, f);
  u += 0x7fffu + ((u >> 16) & 1u);   // RNE
  return (short)(u >> 16);
}
static __device__ __forceinline__ float bf2f(short s) {
  return __builtin_bit_cast(float, ((unsigned)(unsigned short)s) << 16);
}

// barrier that does NOT drain vmcnt; sched_barrier(0) fences motion (rule 18).
#define SBAR() do { \
  __builtin_amdgcn_sched_barrier(0); \
  asm volatile("s_waitcnt lgkmcnt(0)" ::: "memory"); \
  __builtin_amdgcn_s_barrier(); \
  __builtin_amdgcn_sched_barrier(0); \
} while (0)

// ---------------------------------------------------------------------------
// Kernel 1: projections (unchanged, proven).
// ---------------------------------------------------------------------------
#define XSTR 66

__global__ __launch_bounds__(256) void proj_kernel(
    const float* __restrict__ x,
    const float* __restrict__ Wq, const float* __restrict__ bq,
    const float* __restrict__ Wk, const float* __restrict__ bk,
    const float* __restrict__ Wv, const float* __restrict__ bv,
    unsigned short* __restrict__ qh_, unsigned short* __restrict__ ql_,
    unsigned short* __restrict__ kh_, unsigned short* __restrict__ kl_,
    unsigned short* __restrict__ v5)
{
  __shared__ float xs[256 * XSTR];
  const int t = threadIdx.x;
  const int b = blockIdx.x >> 6;
  const int n0 = (blockIdx.x & 63) << 6;
  const float L2E = 1.4426950408889634f;

  const float* xb = x + ((size_t)b * CC) * NNq + n0;
#pragma unroll
  for (int i = 0; i < 16; ++i) {
    int fi = i * 256 + t;
    int c = fi >> 4, nv = (fi & 15) << 2;
    float4 v4 = *(const float4*)(xb + (size_t)c * NNq + nv);
    float* d = &xs[c * XSTR + nv];
    d[0] = v4.x; d[1] = v4.y; d[2] = v4.z; d[3] = v4.w;
  }
  __syncthreads();

  const int w = t >> 6, l = t & 63;
  const int l15 = l & 15, l4 = l >> 4;

  f32x4 acc[5][4];
#pragma unroll
  for (int r5 = 0; r5 < 5; ++r5) {
    int rt = w * 5 + r5;
    const float* bias; float bscale;
    if (rt < 16)      { bias = bv + rt * 16;        bscale = 1.f; }
    else if (rt < 18) { bias = bq + (rt - 16) * 16; bscale = L2E; }
    else              { bias = bk + (rt - 18) * 16; bscale = 1.f; }
#pragma unroll
    for (int j = 0; j < 4; ++j) {
      float bval = bias[l4 * 4 + j] * bscale;
#pragma unroll
      for (int nt = 0; nt < 4; ++nt) acc[r5][nt][j] = bval;
    }
  }

#pragma unroll 1
  for (int ks = 0; ks < 8; ++ks) {
    bf16x8 ah[5], al[5];
#pragma unroll
    for (int r5 = 0; r5 < 5; ++r5) {
      int rt = w * 5 + r5;
      const float* wrow; float wscale;
      if (rt < 16)      { wrow = Wv + (size_t)(rt * 16 + l15) * 256;        wscale = 1.f; }
      else if (rt < 18) { wrow = Wq + (size_t)((rt - 16) * 16 + l15) * 256; wscale = L2E; }
      else              { wrow = Wk + (size_t)((rt - 18) * 16 + l15) * 256; wscale = 1.f; }
      const float* src = wrow + ks * 32 + l4 * 8;
#pragma unroll
      for (int i = 0; i < 8; ++i) {
        float v = src[i] * wscale;
        short hh = f2bf(v);
        ah[r5][i] = hh;
        al[r5][i] = f2bf(v - bf2f(hh));
      }
    }
#pragma unroll
    for (int nt = 0; nt < 4; ++nt) {
      bf16x8 bh, bl;
#pragma unroll
      for (int i = 0; i < 8; ++i) {
        float v = xs[(ks * 32 + l4 * 8 + i) * XSTR + nt * 16 + l15];
        short hh = f2bf(v);
        bh[i] = hh;
        bl[i] = f2bf(v - bf2f(hh));
      }
#pragma unroll
      for (int r5 = 0; r5 < 5; ++r5) {
        acc[r5][nt] = MFMA16(ah[r5], bl, acc[r5][nt]);
        acc[r5][nt] = MFMA16(al[r5], bh, acc[r5][nt]);
        acc[r5][nt] = MFMA16(ah[r5], bh, acc[r5][nt]);
      }
    }
  }

#pragma unroll
  for (int r5 = 0; r5 < 5; ++r5) {
    int rt = w * 5 + r5;
#pragma unroll
    for (int nt = 0; nt < 4; ++nt) {
      int n = n0 + nt * 16 + l15;
#pragma unroll
      for (int j = 0; j < 4; ++j) {
        float v = acc[r5][nt][j];
        int sub = l4 * 4 + j;
        if (rt < 16) {
          int c = rt * 16 + sub;
          size_t o = (((size_t)b * 128 + (n >> 5)) * 256 + c) * 32 + (n & 31);
          v5[o] = (unsigned short)f2bf(v);
        } else {
          short hh = f2bf(v);
          short lo = f2bf(v - bf2f(hh));
          unsigned short* dh = (rt < 18) ? qh_ : kh_;
          unsigned short* dl = (rt < 18) ? ql_ : kl_;
          int d = ((rt < 18) ? (rt - 16) : (rt - 18)) * 16 + sub;
          size_t o = ((size_t)b * NNq + n) * 32 + d;
          dh[o] = (unsigned short)hh;
          dl[o] = (unsigned short)lo;
        }
      }
    }
  }
}

// ---------------------------------------------------------------------------
// Kernel 2: fused stats + attention write + PV + epilogue, with PRODUCER/
// CONSUMER WAVE SPECIALIZATION.
// Block = 512 thr (8 waves) owns (b, 32 rows); grid 512 = 2 blocks/CU.
// Pass 1 (all 8 waves, r9-proven): row sums, m-split 8-way, fixed shift 64.
// Pass 2, per 128-m chunk, ONE SBAR per chunk:
//  waves 0-3 (PRODUCERS, role g=pw>>1 rows, h=pw&1 m-half): k loads (2-ahead),
//    4x split-MFMA E sub-tiles, exp2 -> normalized attention nontemporal
//    stores + p-> double-buffered XOR-swizzled LDS tile.
//  waves 4-7 (CONSUMERS, 64 c each): 16 contiguous-1KB v frags (1 chunk
//    slack), 8 swizzled ds_reads, 32 PV-MFMA (setprio(1) — true role
//    diversity now). Steady state: E(i+1) || PV(i) across the barrier; the
//    per-wave serial chain (r9's limiter: E->exp->LDS->barrier->PV in every
//    wave) is halved; iteration ~ max(phase) not sum.
// ---------------------------------------------------------------------------
__global__ __launch_bounds__(512, 4) void attn_pv_kernel(
    const unsigned short* __restrict__ qh_, const unsigned short* __restrict__ ql_,
    const unsigned short* __restrict__ kh_, const unsigned short* __restrict__ kl_,
    const unsigned short* __restrict__ v5, const float* __restrict__ x,
    const float* __restrict__ gamma, float* __restrict__ out)
{
  __shared__ __align__(16) unsigned short p_lds[2][4096]; // [par][32 n][128 m] bf16, XOR-swz
  __shared__ float sums_lds[8][32];

  const int t = threadIdx.x, w = t >> 6, l = t & 63;
  const int l15 = l & 15, l4 = l >> 4;
  const int sb = ((blockIdx.x & 7) << 6) | (blockIdx.x >> 3);  // 512%8==0, bijective
  const int b = sb >> 7;
  const int n0 = (sb & 127) << 5;

  const unsigned short* khb = kh_ + (size_t)b * NNq * 32;
  const unsigned short* klb = kl_ + (size_t)b * NNq * 32;
  const unsigned short* vbb = v5 + (size_t)b * 1048576;
  float* attn = out + 8388608 + (size_t)b * NNq * NNq + (size_t)n0 * NNq;

  // q fragments for both row groups (pass 1 uses both; producers keep own g)
  bf16x8 q2h[2], q2l[2];
#pragma unroll
  for (int rg = 0; rg < 2; ++rg) {
    size_t qo = ((size_t)b * NNq + n0 + rg * 16 + l15) * 32 + l4 * 8;
    q2h[rg] = *(const bf16x8*)(qh_ + qo);
    q2l[rg] = *(const bf16x8*)(ql_ + qo);
  }

  // ---------------- pass 1: row sums; wave owns m in [w*512, w*512+512) -----
  float sx[2][4] = {{0.f,0.f,0.f,0.f},{0.f,0.f,0.f,0.f}};
  {
    const int mq = w * 512;
    bf16x8 kch[2], kcl[2];
#pragma unroll
    for (int mt = 0; mt < 2; ++mt) {
      size_t ko = (size_t)(mq + mt * 16 + l15) * 32 + l4 * 8;
      kch[mt] = *(const bf16x8*)(khb + ko);
      kcl[mt] = *(const bf16x8*)(klb + ko);
    }
#pragma unroll 1
    for (int it = 0; it < 16; ++it) {
      const int nx = mq + ((it + 1) & 15) * 32;
      bf16x8 knh[2], knl[2];
#pragma unroll
      for (int mt = 0; mt < 2; ++mt) {
        size_t ko = (size_t)(nx + mt * 16 + l15) * 32 + l4 * 8;
        knh[mt] = *(const bf16x8*)(khb + ko);
        knl[mt] = *(const bf16x8*)(klb + ko);
      }
#pragma unroll
      for (int mt = 0; mt < 2; ++mt) {
#pragma unroll
        for (int rg = 0; rg < 2; ++rg) {
          f32x4 e = {0.f, 0.f, 0.f, 0.f};
          e = MFMA16(q2h[rg], kcl[mt], e);
          e = MFMA16(q2l[rg], kch[mt], e);
          e = MFMA16(q2h[rg], kch[mt], e);
#pragma unroll
          for (int j = 0; j < 4; ++j) sx[rg][j] += exp2f(e[j] - 64.0f);
        }
      }
      kch[0] = knh[0]; kch[1] = knh[1];
      kcl[0] = knl[0]; kcl[1] = knl[1];
    }
  }
#pragma unroll
  for (int mask = 1; mask < 16; mask <<= 1)
#pragma unroll
    for (int rg = 0; rg < 2; ++rg)
#pragma unroll
      for (int j = 0; j < 4; ++j) sx[rg][j] += __shfl_xor(sx[rg][j], mask);
  if (l15 == 0) {
#pragma unroll
    for (int rg = 0; rg < 2; ++rg)
#pragma unroll
      for (int j = 0; j < 4; ++j)
        sums_lds[w][rg * 16 + l4 * 4 + j] = sx[rg][j];
  }
  __syncthreads();

  // ---------------- pass 2: role-split pipelined attention + PV -------------
  if (w < 4) {
    // ======================= PRODUCER =======================
    const int g = w >> 1, h = w & 1;
    const bf16x8 qh = q2h[g], qlo = q2l[g];
    f32x4 crow;
#pragma unroll
    for (int j = 0; j < 4; ++j) {
      int r = g * 16 + l4 * 4 + j;
      float S = 0.f;
#pragma unroll
      for (int ww = 0; ww < 8; ++ww) S += sums_lds[ww][r];
      crow[j] = 64.0f + log2f(S);
    }

    bf16x8 kAh[4], kAl[4];
    bf16x8 pwv[2];   // packed p for 4 sub-tiles (subs 0,1 | subs 2,3)

    auto loadK = [&](int chunk, bf16x8 (&KH)[4], bf16x8 (&KL)[4]) {
#pragma unroll
      for (int sub = 0; sub < 4; ++sub) {
        size_t ko = (size_t)(chunk * 128 + h * 64 + sub * 16 + l15) * 32 + l4 * 8;
        KH[sub] = *(const bf16x8*)(khb + ko);
        KL[sub] = *(const bf16x8*)(klb + ko);
      }
    };
    auto estep = [&](int ec, const bf16x8 (&KH)[4], const bf16x8 (&KL)[4]) {
#pragma unroll
      for (int sub = 0; sub < 4; ++sub) {
        f32x4 e = {0.f, 0.f, 0.f, 0.f};
        e = MFMA16(qh, KL[sub], e);
        e = MFMA16(qlo, KH[sub], e);
        e = MFMA16(qh, KH[sub], e);
#pragma unroll
        for (int j = 0; j < 4; ++j) {
          float p = exp2f(e[j] - crow[j]);
          int nl = g * 16 + l4 * 4 + j;
          int ml = h * 64 + sub * 16 + l15;
          __builtin_nontemporal_store(p, attn + (size_t)nl * NNq + ec * 128 + ml);
          pwv[sub >> 1][(sub & 1) * 4 + j] = f2bf(p);
        }
      }
    };
    auto pwrite = [&](int par) {
      char* pld = (char*)p_lds[par];
#pragma unroll
      for (int sub = 0; sub < 4; ++sub)
#pragma unroll
        for (int j = 0; j < 4; ++j) {
          int nl = g * 16 + l4 * 4 + j;
          int ml = h * 64 + sub * 16 + l15;
          int byteo = nl * 256 + ((ml * 2) ^ ((nl & 7) << 4));
          *(unsigned short*)(pld + byteo) =
              (unsigned short)pwv[sub >> 1][(sub & 1) * 4 + j];
        }
    };

    // prologue
    loadK(0, kAh, kAl);
    estep(0, kAh, kAl);
    pwrite(0);
    loadK(1, kAh, kAl);

#pragma unroll 1
    for (int it = 0; it < 32; ++it) {
      bf16x8 kBh[4], kBl[4];
      loadK((it + 2) & 31, kBh, kBl);
      if (it < 31) estep(it + 1, kAh, kAl);
      SBAR();
      if (it < 31) pwrite((it + 1) & 1);
#pragma unroll
      for (int sub = 0; sub < 4; ++sub) { kAh[sub] = kBh[sub]; kAl[sub] = kBl[sub]; }
    }
  } else {
    // ======================= CONSUMER =======================
    const int cw = w - 4;
    f32x4 acc[4][2];   // c = cw*64 + ct*16 + l4*4 + j ; n = n0 + nt*16 + l15
#pragma unroll
    for (int ct = 0; ct < 4; ++ct)
#pragma unroll
      for (int nt = 0; nt < 2; ++nt) acc[ct][nt] = f32x4{0.f, 0.f, 0.f, 0.f};

    bf16x8 vf[4][4];
    auto vload = [&](int chunk) {
#pragma unroll
      for (int ct = 0; ct < 4; ++ct)
#pragma unroll
        for (int ms = 0; ms < 4; ++ms) {
          size_t vo = (size_t)(chunk * 4 + ms) * 8192 +
                      (size_t)(cw * 64 + ct * 16 + l15) * 32 + l4 * 8;
          vf[ct][ms] = *(const bf16x8*)(vbb + vo);
        }
    };
    vload(0);

#pragma unroll 1
    for (int it = 0; it < 32; ++it) {
      SBAR();
      char* pl = (char*)p_lds[it & 1];
      __builtin_amdgcn_s_setprio(1);
#pragma unroll
      for (int ms = 0; ms < 4; ++ms) {
        int mbyte = ms * 64 + l4 * 16;
        int o0 = l15 * 256 + (mbyte ^ ((l15 & 7) << 4));
        int o1 = (16 + l15) * 256 + (mbyte ^ (((16 + l15) & 7) << 4));
        bf16x8 pf0 = *(const bf16x8*)(pl + o0);
        bf16x8 pf1 = *(const bf16x8*)(pl + o1);
#pragma unroll
        for (int ct = 0; ct < 4; ++ct) {
          acc[ct][0] = MFMA16(vf[ct][ms], pf0, acc[ct][0]);
          acc[ct][1] = MFMA16(vf[ct][ms], pf1, acc[ct][1]);
        }
      }
      __builtin_amdgcn_s_setprio(0);
      if (it < 31) vload(it + 1);   // slack = rest of iter + producer E-phase
    }

    // epilogue: weighted = gamma*pv ; final = weighted + x
    const float gm = gamma[0];
#pragma unroll
    for (int ct = 0; ct < 4; ++ct) {
#pragma unroll
      for (int nt = 0; nt < 2; ++nt) {
#pragma unroll
        for (int j = 0; j < 4; ++j) {
          int c = cw * 64 + ct * 16 + l4 * 4 + j;
          int n = n0 + nt * 16 + l15;
          size_t go = ((size_t)b * CC + c) * NNq + n;
          float o = acc[ct][nt][j] * gm;
          out[4194304 + go] = o;
          out[go] = o + x[go];
        }
      }
    }
  }
}

extern "C" void kernel_launch(void* const* d_in, const int* in_sizes, int n_in,
                              void* d_out, int out_size, void* d_ws, size_t ws_size,
                              hipStream_t stream) {
  const float* x     = (const float*)d_in[0];
  const float* Wq    = (const float*)d_in[1];
  const float* bq    = (const float*)d_in[2];
  const float* Wk    = (const float*)d_in[3];
  const float* bk    = (const float*)d_in[4];
  const float* Wv    = (const float*)d_in[5];
  const float* bv    = (const float*)d_in[6];
  const float* gamma = (const float*)d_in[7];
  float* out = (float*)d_out;

  char* ws = (char*)d_ws;
  unsigned short* qh   = (unsigned short*)(ws);                    // 1 MB
  unsigned short* ql   = (unsigned short*)(ws + (1u << 20));       // 1 MB
  unsigned short* kh   = (unsigned short*)(ws + (2u << 20));       // 1 MB
  unsigned short* kl   = (unsigned short*)(ws + (3u << 20));       // 1 MB
  unsigned short* v5   = (unsigned short*)(ws + (4u << 20));       // 8 MB

  proj_kernel<<<256, 256, 0, stream>>>(x, Wq, bq, Wk, bk, Wv, bv, qh, ql, kh, kl, v5);
  attn_pv_kernel<<<512, 512, 0, stream>>>(qh, ql, kh, kl, v5, x, gamma, out);
}